// Round 3
// baseline (382.259 us; speedup 1.0000x reference)
//
#include <hip/hip_runtime.h>

// ---------------------------------------------------------------------------
// MultiHeadAttention: B=8, S=1024, D=1024, H=16, dh=64
// outputs: out [8,1024,1024] f32, qk [8,16,1024,1024] f32 (concat in d_out)
// ---------------------------------------------------------------------------

typedef unsigned short u16;
typedef unsigned int   u32;
typedef __attribute__((ext_vector_type(8)))  __bf16 bf16x8;
typedef __attribute__((ext_vector_type(4)))  float  f32x4;
typedef __attribute__((ext_vector_type(16))) float  f32x16;

__device__ __forceinline__ u16 f2bf(float f) {
  u32 u = __float_as_uint(f);
  u += 0x7FFFu + ((u >> 16) & 1u);   // round-to-nearest-even
  return (u16)(u >> 16);
}
__device__ __forceinline__ float bf2f(u16 v) {
  return __uint_as_float(((u32)v) << 16);
}
__device__ __forceinline__ f32x4 mfma16(bf16x8 a, bf16x8 b, f32x4 c) {
  return __builtin_amdgcn_mfma_f32_16x16x32_bf16(a, b, c, 0, 0, 0);
}
__device__ __forceinline__ f32x16 mfma32(bf16x8 a, bf16x8 b, f32x16 c) {
  return __builtin_amdgcn_mfma_f32_32x32x16_bf16(a, b, c, 0, 0, 0);
}
typedef __attribute__((address_space(3))) u32 lds_u32;
typedef const __attribute__((address_space(1))) u32 glb_u32;
__device__ __forceinline__ void gld_lds16(u16* lds, const u16* g) {
  __builtin_amdgcn_global_load_lds((glb_u32*)g, (lds_u32*)lds, 16, 0, 0);
}
__device__ __forceinline__ bf16x8 ld_bf8(const u16* p) {
  return *(const bf16x8*)p;
}
// barrier that waits only on LDS ops (does NOT drain the qk store stream)
__device__ __forceinline__ void barrier_lds() {
  asm volatile("s_waitcnt lgkmcnt(0)" ::: "memory");
  __builtin_amdgcn_s_barrier();
  __builtin_amdgcn_sched_barrier(0);
}

// ---------------------------------------------------------------------------
// f32 -> bf16 conversion (vectorized, 8 elems/thread)
// ---------------------------------------------------------------------------
__global__ __launch_bounds__(256) void cvt_f32_bf16(
    const float* __restrict__ src, u16* __restrict__ dst, int n) {
  int i = (blockIdx.x * 256 + threadIdx.x) * 8;
  if (i >= n) return;
  const float4* s = (const float4*)(src + i);
  float4 a = s[0], b = s[1];
  u16 r[8];
  r[0] = f2bf(a.x); r[1] = f2bf(a.y); r[2] = f2bf(a.z); r[3] = f2bf(a.w);
  r[4] = f2bf(b.x); r[5] = f2bf(b.y); r[6] = f2bf(b.z); r[7] = f2bf(b.w);
  *(uint4*)(dst + i) = *(const uint4*)r;
}

// ---------------------------------------------------------------------------
// Projection GEMM: C[8192, 3072] = xb @ [Wq;Wk;Wv]^T  (K=1024, BK=32, 128x128)
//   region 0 -> Qb  = (C+bq)*scale   [b*1024+s][h*64+d] bf16 (row-major)
//   region 1 -> Kt2 = C*scale        [bh][g=d>>3][s][e=d&7] bf16
//   region 2 -> V2  = C+bv           [bh][s>>3][d][s&7]     bf16
// ---------------------------------------------------------------------------
__global__ __launch_bounds__(256) void proj_gemm(
    const u16* __restrict__ xb,
    const u16* __restrict__ Wqb, const u16* __restrict__ Wkb,
    const u16* __restrict__ Wvb,
    const float* __restrict__ bq, const float* __restrict__ bv,
    u16* __restrict__ Qb, u16* __restrict__ Kt2, u16* __restrict__ V2) {
  __shared__ u16 As[128][32];
  __shared__ u16 Bs[128][32];
  const int tid  = threadIdx.x;
  const int lane = tid & 63;
  const int wid  = tid >> 6;
  const int c15  = lane & 15, c4 = lane >> 4;
  const int m0   = blockIdx.x * 128;
  const int nv0  = blockIdx.y * 128;          // virtual col in [0,3072)
  const int region = nv0 >> 10;               // 0=q 1=k 2=v (1024-aligned)
  const int nl0  = nv0 & 1023;
  const u16* Wsrc = (region == 0) ? Wqb : (region == 1) ? Wkb : Wvb;
  const int wrow = wid >> 1, wcol = wid & 1;
  const int srow = lane >> 2, scol = (lane & 3) * 8;

  f32x4 acc[4][4] = {};

  for (int k0 = 0; k0 < 1024; k0 += 32) {
#pragma unroll
    for (int j = 0; j < 2; ++j) {
      const int r = 64 * j + 16 * wid;
      gld_lds16(&As[r][0], xb   + (m0  + r + srow) * 1024 + k0 + scol);
      gld_lds16(&Bs[r][0], Wsrc + (nl0 + r + srow) * 1024 + k0 + scol);
    }
    __syncthreads();
    bf16x8 af[4], bfr[4];
#pragma unroll
    for (int a = 0; a < 4; ++a) af[a]  = ld_bf8(&As[64 * wrow + 16 * a + c15][8 * c4]);
#pragma unroll
    for (int b = 0; b < 4; ++b) bfr[b] = ld_bf8(&Bs[64 * wcol + 16 * b + c15][8 * c4]);
#pragma unroll
    for (int a = 0; a < 4; ++a)
#pragma unroll
      for (int b = 0; b < 4; ++b)
        acc[a][b] = mfma16(af[a], bfr[b], acc[a][b]);
    __syncthreads();
  }

  const float kSc = 0.35355339059327373f;  // 64^-0.25
#pragma unroll
  for (int a = 0; a < 4; ++a) {
    const int mg = m0 + 64 * wrow + 16 * a + 4 * c4;
    const int bb = mg >> 10;                 // batch
    const int sl = mg & 1023;                // seq pos (mg%4==0, j adds 0..3)
#pragma unroll
    for (int b = 0; b < 4; ++b) {
      const int nl = 64 * wcol + 16 * b + c15;
      const int nv = nv0 + nl;
      if (region == 0) {
        const float bias = bq[nv];
#pragma unroll
        for (int j = 0; j < 4; ++j)
          Qb[(mg + j) * 1024 + nv] = f2bf((acc[a][b][j] + bias) * kSc);
      } else if (region == 1) {
        const int n = nv - 1024;             // h*64 + d
        // Kt2[((bb*16+h)*8 + (d>>3))][s][d&7]
        u16* kp = Kt2 + (((bb * 16 + (n >> 6)) * 8 + ((n >> 3) & 7)) * 1024 + sl) * 8 + (n & 7);
#pragma unroll
        for (int j = 0; j < 4; ++j)
          kp[j * 8] = f2bf(acc[a][b][j] * kSc);
      } else {
        const int n = nv - 2048;             // h*64 + d
        const float bias = bv[n];
        // V2[((bb*16+h)*128 + (s>>3))][d][s&7]
        u16* vp = V2 + (((bb * 16 + (n >> 6)) * 128 + (sl >> 3)) * 64 + (n & 63)) * 8 + (sl & 7);
        u16 p[4];
#pragma unroll
        for (int j = 0; j < 4; ++j) p[j] = f2bf(acc[a][b][j] + bias);
        *(uint2*)vp = *(const uint2*)p;      // 4 consecutive s, 8B store
      }
    }
  }
}

// ---------------------------------------------------------------------------
// Attention: one block = (b, h, 32-row q-tile). 4 waves.
//  phase 1: S = Q K^T + mask via 32x32x16 MFMA (128B-coalesced qk stores),
//           K fragments from Kt2 (contiguous 512B per load)
//  phase 2: exact softmax from LDS (row max/sum), P back to LDS (unnormalized)
//  phase 3: O = P V / l ; V fragments from V2 (4x256B per load), L2-hot
// ---------------------------------------------------------------------------
__global__ __launch_bounds__(256) void attn_kernel(
    const u16* __restrict__ Qb, const u16* __restrict__ Kt2,
    const u16* __restrict__ V2, const float* __restrict__ mask,
    float* __restrict__ qk, u16* __restrict__ WV) {
  __shared__ u16 S_lds[32][1032];            // 66 KB
  __shared__ float inv_l[32];
  const int tid  = threadIdx.x;
  const int lane = tid & 63;
  const int w    = tid >> 6;
  const int c15  = lane & 15, c4 = lane >> 4;
  const int r31  = lane & 31, hi = lane >> 5;
  const int qt = blockIdx.x, h = blockIdx.y, b = blockIdx.z;
  const int q0  = qt * 32;
  const int bs0 = b * 1024;
  const int bh  = b * 16 + h;

  // ---- phase 1: QK^T with 32x32x16; wave w covers s_k in [256w, 256w+256)
  // A-frag: rows q0+r31, d = 16*kk + 8*hi + e
  bf16x8 qf[4];
#pragma unroll
  for (int kk = 0; kk < 4; ++kk)
    qf[kk] = ld_bf8(&Qb[(bs0 + q0 + r31) * 1024 + h * 64 + 16 * kk + 8 * hi]);

  const float* mrow = mask + q0 * 1024;
  float* qkrow = qk + (bh * 1024 + q0) * 1024;
  const u16* kbase = Kt2 + bh * 8 * 1024 * 8;

  for (int c = 0; c < 8; ++c) {
    const int sk0 = 256 * w + 32 * c;
    bf16x8 kf[4];
#pragma unroll
    for (int kk = 0; kk < 4; ++kk)
      kf[kk] = ld_bf8(kbase + ((2 * kk + hi) * 1024 + sk0 + r31) * 8);
    f32x16 acc = {};
#pragma unroll
    for (int kk = 0; kk < 4; ++kk)
      acc = mfma32(qf[kk], kf[kk], acc);
    const int col = sk0 + r31;
#pragma unroll
    for (int reg = 0; reg < 16; ++reg) {
      const int row = (reg & 3) + 8 * (reg >> 2) + 4 * hi;
      const float v = acc[reg] + mrow[row * 1024 + col];
      qkrow[row * 1024 + col] = v;           // 64 lanes -> 2 x 128B segments
      S_lds[row][col] = f2bf(v);
    }
  }
  barrier_lds();                             // qk stores keep draining

  // ---- phase 2: softmax (8 threads per row)
  {
    const int row = tid >> 3, sub = tid & 7;
    float m = -1e30f;
#pragma unroll 4
    for (int i = 0; i < 16; ++i) {
      bf16x8 v = ld_bf8(&S_lds[row][(sub + 8 * i) * 8]);
      const u16* vu = (const u16*)&v;
#pragma unroll
      for (int e = 0; e < 8; ++e) m = fmaxf(m, bf2f(vu[e]));
    }
    m = fmaxf(m, __shfl_xor(m, 1, 8));
    m = fmaxf(m, __shfl_xor(m, 2, 8));
    m = fmaxf(m, __shfl_xor(m, 4, 8));
    float s = 0.f;
#pragma unroll 4
    for (int i = 0; i < 16; ++i) {
      bf16x8 v = ld_bf8(&S_lds[row][(sub + 8 * i) * 8]);
      const u16* vu = (const u16*)&v;
      u16 p[8];
#pragma unroll
      for (int e = 0; e < 8; ++e) {
        const float pe = __expf(bf2f(vu[e]) - m);
        s += pe;
        p[e] = f2bf(pe);
      }
      *(uint4*)&S_lds[row][(sub + 8 * i) * 8] = *(const uint4*)p;
    }
    s += __shfl_xor(s, 1, 8);
    s += __shfl_xor(s, 2, 8);
    s += __shfl_xor(s, 4, 8);
    if (sub == 0) inv_l[row] = 1.0f / s;
  }
  barrier_lds();

  // ---- phase 3: PV (16x16); wave w computes output cols d in [16w, 16w+16)
  f32x4 oacc[2] = {};
  const u16* v2b = V2 + bh * 128 * 64 * 8;
  const int d = 16 * w + c15;
  for (int t = 0; t < 32; ++t) {
    bf16x8 pa0 = ld_bf8(&S_lds[c15][32 * t + 8 * c4]);
    bf16x8 pa1 = ld_bf8(&S_lds[16 + c15][32 * t + 8 * c4]);
    bf16x8 vb  = ld_bf8(v2b + ((4 * t + c4) * 64 + d) * 8);
    oacc[0] = mfma16(pa0, vb, oacc[0]);
    oacc[1] = mfma16(pa1, vb, oacc[1]);
  }
#pragma unroll
  for (int a = 0; a < 2; ++a) {
    const int rl = 16 * a + 4 * c4;
#pragma unroll
    for (int j = 0; j < 4; ++j) {
      const float v = oacc[a][j] * inv_l[rl + j];
      WV[(bs0 + q0 + rl + j) * 1024 + h * 64 + d] = f2bf(v);
    }
  }
}

// ---------------------------------------------------------------------------
// Output GEMM: out[8192,1024] = WV @ Wo^T + bo  (f32 out)
// ---------------------------------------------------------------------------
__global__ __launch_bounds__(256) void out_gemm(
    const u16* __restrict__ Ab, const u16* __restrict__ Wb,
    const float* __restrict__ bias, float* __restrict__ outp) {
  __shared__ u16 As[128][32];
  __shared__ u16 Bs[128][32];
  const int tid  = threadIdx.x;
  const int lane = tid & 63;
  const int wid  = tid >> 6;
  const int c15  = lane & 15, c4 = lane >> 4;
  const int m0   = blockIdx.x * 128;
  const int n0   = blockIdx.y * 128;
  const int wrow = wid >> 1, wcol = wid & 1;
  const int srow = lane >> 2, scol = (lane & 3) * 8;

  f32x4 acc[4][4] = {};

  for (int k0 = 0; k0 < 1024; k0 += 32) {
#pragma unroll
    for (int j = 0; j < 2; ++j) {
      const int r = 64 * j + 16 * wid;
      gld_lds16(&As[r][0], Ab + (m0 + r + srow) * 1024 + k0 + scol);
      gld_lds16(&Bs[r][0], Wb + (n0 + r + srow) * 1024 + k0 + scol);
    }
    __syncthreads();
    bf16x8 af[4], bfr[4];
#pragma unroll
    for (int a = 0; a < 4; ++a) af[a]  = ld_bf8(&As[64 * wrow + 16 * a + c15][8 * c4]);
#pragma unroll
    for (int b = 0; b < 4; ++b) bfr[b] = ld_bf8(&Bs[64 * wcol + 16 * b + c15][8 * c4]);
#pragma unroll
    for (int a = 0; a < 4; ++a)
#pragma unroll
      for (int b = 0; b < 4; ++b)
        acc[a][b] = mfma16(af[a], bfr[b], acc[a][b]);
    __syncthreads();
  }

#pragma unroll
  for (int a = 0; a < 4; ++a) {
    const int mg = m0 + 64 * wrow + 16 * a + 4 * c4;
#pragma unroll
    for (int b = 0; b < 4; ++b) {
      const int ng = n0 + 64 * wcol + 16 * b + c15;
      const float bi = bias[ng];
#pragma unroll
      for (int j = 0; j < 4; ++j)
        outp[(mg + j) * 1024 + ng] = acc[a][b][j] + bi;
    }
  }
}

// ---------------------------------------------------------------------------
extern "C" void kernel_launch(void* const* d_in, const int* in_sizes, int n_in,
                              void* d_out, int out_size, void* d_ws, size_t ws_size,
                              hipStream_t stream) {
  const float* x    = (const float*)d_in[0];
  const float* mask = (const float*)d_in[1];
  const float* Wq   = (const float*)d_in[2];
  const float* bq   = (const float*)d_in[3];
  const float* Wk   = (const float*)d_in[4];
  const float* Wv   = (const float*)d_in[5];
  const float* bv   = (const float*)d_in[6];
  const float* Wo   = (const float*)d_in[7];
  const float* bo   = (const float*)d_in[8];

  float* outp = (float*)d_out;
  float* qk   = outp + 8 * 1024 * 1024;      // second output

  // workspace (bf16 elements): ~88 MB total
  u16* ws  = (u16*)d_ws;
  u16* xb  = ws;                    // 8388608
  u16* Wqb = xb  + 8388608;         // 1048576
  u16* Wkb = Wqb + 1048576;
  u16* Wvb = Wkb + 1048576;
  u16* Wob = Wvb + 1048576;
  u16* Qb  = Wob + 1048576;         // 8388608 (scaled)
  u16* Kt2 = Qb  + 8388608;         // 8388608 ([bh][d>>3][s][d&7], scaled)
  u16* V2  = Kt2 + 8388608;         // 8388608 ([bh][s>>3][d][s&7])
  u16* WV  = V2  + 8388608;         // 8388608

  cvt_f32_bf16<<<4096, 256, 0, stream>>>(x,  xb,  8388608);
  cvt_f32_bf16<<<512,  256, 0, stream>>>(Wq, Wqb, 1048576);
  cvt_f32_bf16<<<512,  256, 0, stream>>>(Wk, Wkb, 1048576);
  cvt_f32_bf16<<<512,  256, 0, stream>>>(Wv, Wvb, 1048576);
  cvt_f32_bf16<<<512,  256, 0, stream>>>(Wo, Wob, 1048576);

  proj_gemm<<<dim3(64, 24), 256, 0, stream>>>(xb, Wqb, Wkb, Wvb, bq, bv, Qb, Kt2, V2);
  attn_kernel<<<dim3(32, 16, 8), 256, 0, stream>>>(Qb, Kt2, V2, mask, qk, WV);
  out_gemm<<<dim3(64, 8), 256, 0, stream>>>(WV, Wob, bo, outp);
}

// Round 4
// 377.786 us; speedup vs baseline: 1.0118x; 1.0118x over previous
//
#include <hip/hip_runtime.h>

// ---------------------------------------------------------------------------
// MultiHeadAttention: B=8, S=1024, D=1024, H=16, dh=64
// outputs: out [8,1024,1024] f32, qk [8,16,1024,1024] f32 (concat in d_out)
// ---------------------------------------------------------------------------

typedef unsigned short u16;
typedef unsigned int   u32;
typedef __attribute__((ext_vector_type(8)))  __bf16 bf16x8;
typedef __attribute__((ext_vector_type(4)))  float  f32x4;
typedef __attribute__((ext_vector_type(16))) float  f32x16;

__device__ __forceinline__ u16 f2bf(float f) {
  u32 u = __float_as_uint(f);
  u += 0x7FFFu + ((u >> 16) & 1u);   // round-to-nearest-even
  return (u16)(u >> 16);
}
__device__ __forceinline__ float bf2f(u16 v) {
  return __uint_as_float(((u32)v) << 16);
}
__device__ __forceinline__ f32x4 mfma16(bf16x8 a, bf16x8 b, f32x4 c) {
  return __builtin_amdgcn_mfma_f32_16x16x32_bf16(a, b, c, 0, 0, 0);
}
__device__ __forceinline__ f32x16 mfma32(bf16x8 a, bf16x8 b, f32x16 c) {
  return __builtin_amdgcn_mfma_f32_32x32x16_bf16(a, b, c, 0, 0, 0);
}
typedef __attribute__((address_space(3))) u32 lds_u32;
typedef const __attribute__((address_space(1))) u32 glb_u32;
__device__ __forceinline__ void gld_lds16(u16* lds, const u16* g) {
  __builtin_amdgcn_global_load_lds((glb_u32*)g, (lds_u32*)lds, 16, 0, 0);
}
__device__ __forceinline__ bf16x8 ld_bf8(const u16* p) {
  return *(const bf16x8*)p;
}
// barrier that waits only on LDS ops (does NOT drain the qk store stream)
__device__ __forceinline__ void barrier_lds() {
  asm volatile("s_waitcnt lgkmcnt(0)" ::: "memory");
  __builtin_amdgcn_s_barrier();
  __builtin_amdgcn_sched_barrier(0);
}

// ---------------------------------------------------------------------------
// f32 -> bf16 conversion (vectorized, 8 elems/thread)
// ---------------------------------------------------------------------------
__global__ __launch_bounds__(256) void cvt_f32_bf16(
    const float* __restrict__ src, u16* __restrict__ dst, int n) {
  int i = (blockIdx.x * 256 + threadIdx.x) * 8;
  if (i >= n) return;
  const float4* s = (const float4*)(src + i);
  float4 a = s[0], b = s[1];
  u16 r[8];
  r[0] = f2bf(a.x); r[1] = f2bf(a.y); r[2] = f2bf(a.z); r[3] = f2bf(a.w);
  r[4] = f2bf(b.x); r[5] = f2bf(b.y); r[6] = f2bf(b.z); r[7] = f2bf(b.w);
  *(uint4*)(dst + i) = *(const uint4*)r;
}

// ---------------------------------------------------------------------------
// Projection GEMM: C[8192, 3072] = xb @ [Wq;Wk;Wv]^T  (K=1024, BK=32, 128x128)
// 2-phase pipelined: double-buffered LDS, stage(next) issued BEFORE compute,
// single __syncthreads per K-iter (vmcnt(0) drains after MFMA, not before).
//   region 0 -> Qb  = (C+bq)*scale   [b*1024+s][h*64+d] bf16 (row-major)
//   region 1 -> Kt2 = C*scale        [bh][g=d>>3][s][e=d&7] bf16
//   region 2 -> V2  = C+bv           [bh][s>>3][d][s&7]     bf16
// ---------------------------------------------------------------------------
__global__ __launch_bounds__(256) void proj_gemm(
    const u16* __restrict__ xb,
    const u16* __restrict__ Wqb, const u16* __restrict__ Wkb,
    const u16* __restrict__ Wvb,
    const float* __restrict__ bq, const float* __restrict__ bv,
    u16* __restrict__ Qb, u16* __restrict__ Kt2, u16* __restrict__ V2) {
  __shared__ u16 As[2][128][32];
  __shared__ u16 Bs[2][128][32];
  const int tid  = threadIdx.x;
  const int lane = tid & 63;
  const int wid  = tid >> 6;
  const int c15  = lane & 15, c4 = lane >> 4;
  const int m0   = blockIdx.x * 128;
  const int nv0  = blockIdx.y * 128;          // virtual col in [0,3072)
  const int region = nv0 >> 10;               // 0=q 1=k 2=v (1024-aligned)
  const int nl0  = nv0 & 1023;
  const u16* Wsrc = (region == 0) ? Wqb : (region == 1) ? Wkb : Wvb;
  const int wrow = wid >> 1, wcol = wid & 1;
  const int srow = lane >> 2, scol = (lane & 3) * 8;

  const u16* aptr = xb   + (m0  + srow) * 1024 + scol;
  const u16* bptr = Wsrc + (nl0 + srow) * 1024 + scol;

  f32x4 acc[4][4] = {};

  // prologue: stage k0=0 into buf 0
#pragma unroll
  for (int j = 0; j < 2; ++j) {
    const int r = 64 * j + 16 * wid;
    gld_lds16(&As[0][r][0], aptr + r * 1024);
    gld_lds16(&Bs[0][r][0], bptr + r * 1024);
  }
  __syncthreads();

  int cur = 0;
  for (int k0 = 0; k0 < 1024; k0 += 32) {
    if (k0 + 32 < 1024) {
      const int nxt = cur ^ 1;
#pragma unroll
      for (int j = 0; j < 2; ++j) {
        const int r = 64 * j + 16 * wid;
        gld_lds16(&As[nxt][r][0], aptr + r * 1024 + k0 + 32);
        gld_lds16(&Bs[nxt][r][0], bptr + r * 1024 + k0 + 32);
      }
    }
    bf16x8 af[4], bfr[4];
#pragma unroll
    for (int a = 0; a < 4; ++a) af[a]  = ld_bf8(&As[cur][64 * wrow + 16 * a + c15][8 * c4]);
#pragma unroll
    for (int b = 0; b < 4; ++b) bfr[b] = ld_bf8(&Bs[cur][64 * wcol + 16 * b + c15][8 * c4]);
#pragma unroll
    for (int a = 0; a < 4; ++a)
#pragma unroll
      for (int b = 0; b < 4; ++b)
        acc[a][b] = mfma16(af[a], bfr[b], acc[a][b]);
    __syncthreads();   // vmcnt(0): next-tile loads done; lgkm: reads done
    cur ^= 1;
  }

  const float kSc = 0.35355339059327373f;  // 64^-0.25
#pragma unroll
  for (int a = 0; a < 4; ++a) {
    const int mg = m0 + 64 * wrow + 16 * a + 4 * c4;
    const int bb = mg >> 10;                 // batch
    const int sl = mg & 1023;                // seq pos (mg%4==0, j adds 0..3)
#pragma unroll
    for (int b = 0; b < 4; ++b) {
      const int nl = 64 * wcol + 16 * b + c15;
      const int nv = nv0 + nl;
      if (region == 0) {
        const float bias = bq[nv];
#pragma unroll
        for (int j = 0; j < 4; ++j)
          Qb[(mg + j) * 1024 + nv] = f2bf((acc[a][b][j] + bias) * kSc);
      } else if (region == 1) {
        const int n = nv - 1024;             // h*64 + d
        u16* kp = Kt2 + (((bb * 16 + (n >> 6)) * 8 + ((n >> 3) & 7)) * 1024 + sl) * 8 + (n & 7);
#pragma unroll
        for (int j = 0; j < 4; ++j)
          kp[j * 8] = f2bf(acc[a][b][j] * kSc);
      } else {
        const int n = nv - 2048;             // h*64 + d
        const float bias = bv[n];
        u16* vp = V2 + (((bb * 16 + (n >> 6)) * 128 + (sl >> 3)) * 64 + (n & 63)) * 8 + (sl & 7);
        u16 p[4];
#pragma unroll
        for (int j = 0; j < 4; ++j) p[j] = f2bf(acc[a][b][j] + bias);
        *(uint2*)vp = *(const uint2*)p;      // 4 consecutive s, 8B store
      }
    }
  }
}

// ---------------------------------------------------------------------------
// Attention: one block = (b, h, 32-row q-tile). 4 waves.
//  phase 1: S = Q K^T + mask(bf16, L2-resident) via 32x32x16 MFMA
//  phase 2: exact softmax from LDS
//  phase 3: O = P V / l ; V from V2 (L2-hot)
// ---------------------------------------------------------------------------
__global__ __launch_bounds__(256) void attn_kernel(
    const u16* __restrict__ Qb, const u16* __restrict__ Kt2,
    const u16* __restrict__ V2, const u16* __restrict__ maskb,
    float* __restrict__ qk, u16* __restrict__ WV) {
  __shared__ u16 S_lds[32][1032];            // 66 KB
  __shared__ float inv_l[32];
  const int tid  = threadIdx.x;
  const int lane = tid & 63;
  const int w    = tid >> 6;
  const int c15  = lane & 15, c4 = lane >> 4;
  const int r31  = lane & 31, hi = lane >> 5;
  const int qt = blockIdx.x, h = blockIdx.y, b = blockIdx.z;
  const int q0  = qt * 32;
  const int bs0 = b * 1024;
  const int bh  = b * 16 + h;

  // ---- phase 1: QK^T with 32x32x16; wave w covers s_k in [256w, 256w+256)
  bf16x8 qf[4];
#pragma unroll
  for (int kk = 0; kk < 4; ++kk)
    qf[kk] = ld_bf8(&Qb[(bs0 + q0 + r31) * 1024 + h * 64 + 16 * kk + 8 * hi]);

  const u16* mrow = maskb + q0 * 1024;
  float* qkrow = qk + (bh * 1024 + q0) * 1024;
  const u16* kbase = Kt2 + bh * 8 * 1024 * 8;

  for (int c = 0; c < 8; ++c) {
    const int sk0 = 256 * w + 32 * c;
    bf16x8 kf[4];
#pragma unroll
    for (int kk = 0; kk < 4; ++kk)
      kf[kk] = ld_bf8(kbase + ((2 * kk + hi) * 1024 + sk0 + r31) * 8);
    f32x16 acc = {};
#pragma unroll
    for (int kk = 0; kk < 4; ++kk)
      acc = mfma32(qf[kk], kf[kk], acc);
    const int col = sk0 + r31;
#pragma unroll
    for (int reg = 0; reg < 16; ++reg) {
      const int row = (reg & 3) + 8 * (reg >> 2) + 4 * hi;
      const float v = acc[reg] + bf2f(mrow[row * 1024 + col]);
      qkrow[row * 1024 + col] = v;           // 64 lanes -> 2 x 128B segments
      S_lds[row][col] = f2bf(v);
    }
  }
  barrier_lds();                             // qk stores keep draining

  // ---- phase 2: softmax (8 threads per row)
  {
    const int row = tid >> 3, sub = tid & 7;
    float m = -1e30f;
#pragma unroll 4
    for (int i = 0; i < 16; ++i) {
      bf16x8 v = ld_bf8(&S_lds[row][(sub + 8 * i) * 8]);
      const u16* vu = (const u16*)&v;
#pragma unroll
      for (int e = 0; e < 8; ++e) m = fmaxf(m, bf2f(vu[e]));
    }
    m = fmaxf(m, __shfl_xor(m, 1, 8));
    m = fmaxf(m, __shfl_xor(m, 2, 8));
    m = fmaxf(m, __shfl_xor(m, 4, 8));
    float s = 0.f;
#pragma unroll 4
    for (int i = 0; i < 16; ++i) {
      bf16x8 v = ld_bf8(&S_lds[row][(sub + 8 * i) * 8]);
      const u16* vu = (const u16*)&v;
      u16 p[8];
#pragma unroll
      for (int e = 0; e < 8; ++e) {
        const float pe = __expf(bf2f(vu[e]) - m);
        s += pe;
        p[e] = f2bf(pe);
      }
      *(uint4*)&S_lds[row][(sub + 8 * i) * 8] = *(const uint4*)p;
    }
    s += __shfl_xor(s, 1, 8);
    s += __shfl_xor(s, 2, 8);
    s += __shfl_xor(s, 4, 8);
    if (sub == 0) inv_l[row] = 1.0f / s;
  }
  barrier_lds();

  // ---- phase 3: PV (16x16); wave w computes output cols d in [16w, 16w+16)
  f32x4 oacc[2] = {};
  const u16* v2b = V2 + bh * 128 * 64 * 8;
  const int d = 16 * w + c15;
  for (int t = 0; t < 32; ++t) {
    bf16x8 pa0 = ld_bf8(&S_lds[c15][32 * t + 8 * c4]);
    bf16x8 pa1 = ld_bf8(&S_lds[16 + c15][32 * t + 8 * c4]);
    bf16x8 vb  = ld_bf8(v2b + ((4 * t + c4) * 64 + d) * 8);
    oacc[0] = mfma16(pa0, vb, oacc[0]);
    oacc[1] = mfma16(pa1, vb, oacc[1]);
  }
#pragma unroll
  for (int a = 0; a < 2; ++a) {
    const int rl = 16 * a + 4 * c4;
#pragma unroll
    for (int j = 0; j < 4; ++j) {
      const float v = oacc[a][j] * inv_l[rl + j];
      WV[(bs0 + q0 + rl + j) * 1024 + h * 64 + d] = f2bf(v);
    }
  }
}

// ---------------------------------------------------------------------------
// Output GEMM: out[8192,1024] = WV @ Wo^T + bo  (f32 out), 2-phase pipelined
// ---------------------------------------------------------------------------
__global__ __launch_bounds__(256) void out_gemm(
    const u16* __restrict__ Ab, const u16* __restrict__ Wb,
    const float* __restrict__ bias, float* __restrict__ outp) {
  __shared__ u16 As[2][128][32];
  __shared__ u16 Bs[2][128][32];
  const int tid  = threadIdx.x;
  const int lane = tid & 63;
  const int wid  = tid >> 6;
  const int c15  = lane & 15, c4 = lane >> 4;
  const int m0   = blockIdx.x * 128;
  const int n0   = blockIdx.y * 128;
  const int wrow = wid >> 1, wcol = wid & 1;
  const int srow = lane >> 2, scol = (lane & 3) * 8;

  const u16* aptr = Ab + (m0 + srow) * 1024 + scol;
  const u16* bptr = Wb + (n0 + srow) * 1024 + scol;

  f32x4 acc[4][4] = {};

#pragma unroll
  for (int j = 0; j < 2; ++j) {
    const int r = 64 * j + 16 * wid;
    gld_lds16(&As[0][r][0], aptr + r * 1024);
    gld_lds16(&Bs[0][r][0], bptr + r * 1024);
  }
  __syncthreads();

  int cur = 0;
  for (int k0 = 0; k0 < 1024; k0 += 32) {
    if (k0 + 32 < 1024) {
      const int nxt = cur ^ 1;
#pragma unroll
      for (int j = 0; j < 2; ++j) {
        const int r = 64 * j + 16 * wid;
        gld_lds16(&As[nxt][r][0], aptr + r * 1024 + k0 + 32);
        gld_lds16(&Bs[nxt][r][0], bptr + r * 1024 + k0 + 32);
      }
    }
    bf16x8 af[4], bfr[4];
#pragma unroll
    for (int a = 0; a < 4; ++a) af[a]  = ld_bf8(&As[cur][64 * wrow + 16 * a + c15][8 * c4]);
#pragma unroll
    for (int b = 0; b < 4; ++b) bfr[b] = ld_bf8(&Bs[cur][64 * wcol + 16 * b + c15][8 * c4]);
#pragma unroll
    for (int a = 0; a < 4; ++a)
#pragma unroll
      for (int b = 0; b < 4; ++b)
        acc[a][b] = mfma16(af[a], bfr[b], acc[a][b]);
    __syncthreads();
    cur ^= 1;
  }

#pragma unroll
  for (int a = 0; a < 4; ++a) {
    const int mg = m0 + 64 * wrow + 16 * a + 4 * c4;
#pragma unroll
    for (int b = 0; b < 4; ++b) {
      const int ng = n0 + 64 * wcol + 16 * b + c15;
      const float bi = bias[ng];
#pragma unroll
      for (int j = 0; j < 4; ++j)
        outp[(mg + j) * 1024 + ng] = acc[a][b][j] + bi;
    }
  }
}

// ---------------------------------------------------------------------------
extern "C" void kernel_launch(void* const* d_in, const int* in_sizes, int n_in,
                              void* d_out, int out_size, void* d_ws, size_t ws_size,
                              hipStream_t stream) {
  const float* x    = (const float*)d_in[0];
  const float* mask = (const float*)d_in[1];
  const float* Wq   = (const float*)d_in[2];
  const float* bq   = (const float*)d_in[3];
  const float* Wk   = (const float*)d_in[4];
  const float* Wv   = (const float*)d_in[5];
  const float* bv   = (const float*)d_in[6];
  const float* Wo   = (const float*)d_in[7];
  const float* bo   = (const float*)d_in[8];

  float* outp = (float*)d_out;
  float* qk   = outp + 8 * 1024 * 1024;      // second output

  // workspace (bf16 elements): ~94 MB total
  u16* ws    = (u16*)d_ws;
  u16* xb    = ws;                    // 8388608
  u16* Wqb   = xb  + 8388608;         // 1048576
  u16* Wkb   = Wqb + 1048576;
  u16* Wvb   = Wkb + 1048576;
  u16* Wob   = Wvb + 1048576;
  u16* Qb    = Wob + 1048576;         // 8388608 (scaled)
  u16* Kt2   = Qb  + 8388608;         // 8388608 ([bh][d>>3][s][d&7], scaled)
  u16* V2    = Kt2 + 8388608;         // 8388608 ([bh][s>>3][d][s&7])
  u16* WV    = V2  + 8388608;         // 8388608
  u16* maskb = WV  + 8388608;         // 1048576 (bf16 mask, 2 MB: L2-resident)

  cvt_f32_bf16<<<4096, 256, 0, stream>>>(x,    xb,    8388608);
  cvt_f32_bf16<<<512,  256, 0, stream>>>(Wq,   Wqb,   1048576);
  cvt_f32_bf16<<<512,  256, 0, stream>>>(Wk,   Wkb,   1048576);
  cvt_f32_bf16<<<512,  256, 0, stream>>>(Wv,   Wvb,   1048576);
  cvt_f32_bf16<<<512,  256, 0, stream>>>(Wo,   Wob,   1048576);
  cvt_f32_bf16<<<512,  256, 0, stream>>>(mask, maskb, 1048576);

  proj_gemm<<<dim3(64, 24), 256, 0, stream>>>(xb, Wqb, Wkb, Wvb, bq, bv, Qb, Kt2, V2);
  attn_kernel<<<dim3(32, 16, 8), 256, 0, stream>>>(Qb, Kt2, V2, maskb, qk, WV);
  out_gemm<<<dim3(64, 8), 256, 0, stream>>>(WV, Wob, bo, outp);
}

// Round 5
// 364.484 us; speedup vs baseline: 1.0488x; 1.0365x over previous
//
#include <hip/hip_runtime.h>

// ---------------------------------------------------------------------------
// MultiHeadAttention: B=8, S=1024, D=1024, H=16, dh=64
// outputs: out [8,1024,1024] f32, qk [8,16,1024,1024] f32 (concat in d_out)
// ---------------------------------------------------------------------------

typedef unsigned short u16;
typedef unsigned int   u32;
typedef __attribute__((ext_vector_type(8)))  __bf16 bf16x8;
typedef __attribute__((ext_vector_type(4)))  float  f32x4;
typedef __attribute__((ext_vector_type(16))) float  f32x16;

__device__ __forceinline__ u16 f2bf(float f) {
  u32 u = __float_as_uint(f);
  u += 0x7FFFu + ((u >> 16) & 1u);   // round-to-nearest-even
  return (u16)(u >> 16);
}
__device__ __forceinline__ float bf2f(u16 v) {
  return __uint_as_float(((u32)v) << 16);
}
__device__ __forceinline__ u32 pk2(float a, float b) {
  return (u32)f2bf(a) | ((u32)f2bf(b) << 16);
}
__device__ __forceinline__ f32x4 mfma16(bf16x8 a, bf16x8 b, f32x4 c) {
  return __builtin_amdgcn_mfma_f32_16x16x32_bf16(a, b, c, 0, 0, 0);
}
__device__ __forceinline__ f32x16 mfma32(bf16x8 a, bf16x8 b, f32x16 c) {
  return __builtin_amdgcn_mfma_f32_32x32x16_bf16(a, b, c, 0, 0, 0);
}
typedef __attribute__((address_space(3))) u32 lds_u32;
typedef const __attribute__((address_space(1))) u32 glb_u32;
__device__ __forceinline__ void gld_lds16(u16* lds, const u16* g) {
  __builtin_amdgcn_global_load_lds((glb_u32*)g, (lds_u32*)lds, 16, 0, 0);
}
__device__ __forceinline__ bf16x8 ld_bf8(const u16* p) {
  return *(const bf16x8*)p;
}

// ---------------------------------------------------------------------------
// f32 -> bf16 conversion (vectorized, 8 elems/thread)
// ---------------------------------------------------------------------------
__global__ __launch_bounds__(256) void cvt_f32_bf16(
    const float* __restrict__ src, u16* __restrict__ dst, int n) {
  int i = (blockIdx.x * 256 + threadIdx.x) * 8;
  if (i >= n) return;
  const float4* s = (const float4*)(src + i);
  float4 a = s[0], b = s[1];
  u16 r[8];
  r[0] = f2bf(a.x); r[1] = f2bf(a.y); r[2] = f2bf(a.z); r[3] = f2bf(a.w);
  r[4] = f2bf(b.x); r[5] = f2bf(b.y); r[6] = f2bf(b.z); r[7] = f2bf(b.w);
  *(uint4*)(dst + i) = *(const uint4*)r;
}

// ---------------------------------------------------------------------------
// mask [S][S] f32 -> maskT [k][q] bf16 (transposed), 32x32 LDS tiles
// ---------------------------------------------------------------------------
__global__ __launch_bounds__(256) void trans_mask(
    const float* __restrict__ m, u16* __restrict__ mt) {
  __shared__ u16 L[32][33];
  const int x = threadIdx.x & 31, y4 = threadIdx.x >> 5;   // y4: 0..7
  const int r0 = blockIdx.y * 32, c0 = blockIdx.x * 32;
#pragma unroll
  for (int j = 0; j < 4; ++j) {
    const int r = y4 * 4 + j;
    L[x][r] = f2bf(m[(r0 + r) * 1024 + c0 + x]);
  }
  __syncthreads();
#pragma unroll
  for (int j = 0; j < 4; ++j) {
    const int rr = y4 * 4 + j;
    mt[(c0 + rr) * 1024 + r0 + x] = L[rr][x];
  }
}

// ---------------------------------------------------------------------------
// Projection GEMM: C[8192, 3072] = xb @ [Wq;Wk;Wv]^T  (K=1024, BK=32, 128x128)
// 2-phase pipelined (double-buffered LDS, stage-next before compute).
//   region 0 -> Qt2 = (C+bq)*scale  [bh][g=d>>3][s][e=d&7] bf16
//   region 1 -> Kt2 = C*scale       [bh][g=d>>3][s][e=d&7] bf16
//   region 2 -> V2  = C+bv          [bh][s>>3][d][s&7]     bf16
// ---------------------------------------------------------------------------
__global__ __launch_bounds__(256) void proj_gemm(
    const u16* __restrict__ xb,
    const u16* __restrict__ Wqb, const u16* __restrict__ Wkb,
    const u16* __restrict__ Wvb,
    const float* __restrict__ bq, const float* __restrict__ bv,
    u16* __restrict__ Qt2, u16* __restrict__ Kt2, u16* __restrict__ V2) {
  __shared__ u16 As[2][128][32];
  __shared__ u16 Bs[2][128][32];
  const int tid  = threadIdx.x;
  const int lane = tid & 63;
  const int wid  = tid >> 6;
  const int c15  = lane & 15, c4 = lane >> 4;
  const int m0   = blockIdx.x * 128;
  const int nv0  = blockIdx.y * 128;          // virtual col in [0,3072)
  const int region = nv0 >> 10;               // 0=q 1=k 2=v (1024-aligned)
  const int nl0  = nv0 & 1023;
  const u16* Wsrc = (region == 0) ? Wqb : (region == 1) ? Wkb : Wvb;
  const int wrow = wid >> 1, wcol = wid & 1;
  const int srow = lane >> 2, scol = (lane & 3) * 8;

  const u16* aptr = xb   + (m0  + srow) * 1024 + scol;
  const u16* bptr = Wsrc + (nl0 + srow) * 1024 + scol;

  f32x4 acc[4][4] = {};

#pragma unroll
  for (int j = 0; j < 2; ++j) {
    const int r = 64 * j + 16 * wid;
    gld_lds16(&As[0][r][0], aptr + r * 1024);
    gld_lds16(&Bs[0][r][0], bptr + r * 1024);
  }
  __syncthreads();

  int cur = 0;
  for (int k0 = 0; k0 < 1024; k0 += 32) {
    if (k0 + 32 < 1024) {
      const int nxt = cur ^ 1;
#pragma unroll
      for (int j = 0; j < 2; ++j) {
        const int r = 64 * j + 16 * wid;
        gld_lds16(&As[nxt][r][0], aptr + r * 1024 + k0 + 32);
        gld_lds16(&Bs[nxt][r][0], bptr + r * 1024 + k0 + 32);
      }
    }
    bf16x8 af[4], bfr[4];
#pragma unroll
    for (int a = 0; a < 4; ++a) af[a]  = ld_bf8(&As[cur][64 * wrow + 16 * a + c15][8 * c4]);
#pragma unroll
    for (int b = 0; b < 4; ++b) bfr[b] = ld_bf8(&Bs[cur][64 * wcol + 16 * b + c15][8 * c4]);
#pragma unroll
    for (int a = 0; a < 4; ++a)
#pragma unroll
      for (int b = 0; b < 4; ++b)
        acc[a][b] = mfma16(af[a], bfr[b], acc[a][b]);
    __syncthreads();
    cur ^= 1;
  }

  const float kSc = 0.35355339059327373f;  // 64^-0.25
#pragma unroll
  for (int a = 0; a < 4; ++a) {
    const int mg = m0 + 64 * wrow + 16 * a + 4 * c4;
    const int bb = mg >> 10;                 // batch
    const int sl = mg & 1023;                // seq pos (mg%4==0, j adds 0..3)
#pragma unroll
    for (int b = 0; b < 4; ++b) {
      const int nl = 64 * wcol + 16 * b + c15;
      const int nv = nv0 + nl;
      if (region == 0) {
        const int n = nv;                    // h*64 + d
        const float bias = bq[n];
        u16* qp = Qt2 + (((bb * 16 + (n >> 6)) * 8 + ((n >> 3) & 7)) * 1024 + sl) * 8 + (n & 7);
#pragma unroll
        for (int j = 0; j < 4; ++j)
          qp[j * 8] = f2bf((acc[a][b][j] + bias) * kSc);
      } else if (region == 1) {
        const int n = nv - 1024;             // h*64 + d
        u16* kp = Kt2 + (((bb * 16 + (n >> 6)) * 8 + ((n >> 3) & 7)) * 1024 + sl) * 8 + (n & 7);
#pragma unroll
        for (int j = 0; j < 4; ++j)
          kp[j * 8] = f2bf(acc[a][b][j] * kSc);
      } else {
        const int n = nv - 2048;             // h*64 + d
        const float bias = bv[n];
        u16* vp = V2 + (((bb * 16 + (n >> 6)) * 128 + (sl >> 3)) * 64 + (n & 63)) * 8 + (sl & 7);
        u16 p[4];
#pragma unroll
        for (int j = 0; j < 4; ++j) p[j] = f2bf(acc[a][b][j] + bias);
        *(uint2*)vp = *(const uint2*)p;      // 4 consecutive s, 8B store
      }
    }
  }
}

// ---------------------------------------------------------------------------
// Attention v2: 512 thr = 8 independent waves, each owns 32 q-rows.
// Swapped QK^T (A=K, B=Q) -> each lane holds one q-row's scores (16/tile).
// Pass 1: S = K^T Q + mask; running row-max; qk store (coalesced via
//         wave-private LDS transpose tile). No barriers anywhere.
// Pass 2: recompute S, P = exp(S - m) -> bf16 A-frags via pack + shfl_xor(32)
//         half-exchange; PV accumulate; O = PV / l.
// ---------------------------------------------------------------------------
__global__ __launch_bounds__(512) void attn_v2(
    const u16* __restrict__ Qt2, const u16* __restrict__ Kt2,
    const u16* __restrict__ V2, const u16* __restrict__ maskT,
    float* __restrict__ qk, u16* __restrict__ WV) {
  __shared__ float Tb[8][1088];              // per-wave 32x34 f32 (16B-safe via f32x2)
  __shared__ float invl[8][32];
  const int tid  = threadIdx.x;
  const int lane = tid & 63;
  const int w    = tid >> 6;
  const int r31  = lane & 31, hi = lane >> 5;
  const int h = blockIdx.y, b = blockIdx.z;
  const int bh  = b * 16 + h;
  const int q0  = blockIdx.x * 256 + w * 32; // local seq pos of this wave's tile
  const int bs0 = b * 1024;

  const u16* qbase = Qt2 + (size_t)bh * 65536;
  const u16* kbase = Kt2 + (size_t)bh * 65536;
  const u16* vbase = V2  + (size_t)bh * 65536;
  float* Tw = Tb[w];
  float* qkbase = qk + ((size_t)bh * 1024 + q0) * 1024;

  // Q fragments (B-operand): lane r31 = q-col, elems d = 16kk+8hi+e
  bf16x8 qf[4];
#pragma unroll
  for (int kk = 0; kk < 4; ++kk)
    qf[kk] = ld_bf8(qbase + ((2 * kk + hi) * 1024 + q0 + r31) * 8);

  // ---- pass 1: S + mask -> row max + coalesced qk store ----
  float mrun = -3e38f;
  for (int c = 0; c < 32; ++c) {
    bf16x8 kf[4];
#pragma unroll
    for (int kk = 0; kk < 4; ++kk)
      kf[kk] = ld_bf8(kbase + ((2 * kk + hi) * 1024 + 32 * c + r31) * 8);
    f32x16 acc = {};
#pragma unroll
    for (int kk = 0; kk < 4; ++kk)
      acc = mfma32(kf[kk], qf[kk], acc);     // C: row=k, col=q(lane)
#pragma unroll
    for (int r = 0; r < 16; ++r) {
      const int kr = (r & 3) + 8 * (r >> 2) + 4 * hi;
      const float v = acc[r] + bf2f(maskT[(32 * c + kr) * 1024 + q0 + r31]);
      mrun = fmaxf(mrun, v);
      Tw[r31 * 34 + kr] = v;                 // T[q][k]
    }
    // read back transposed rows -> 128B-coalesced qk stores (wave-private)
#pragma unroll
    for (int qi = 0; qi < 4; ++qi) {
      const int qq = 8 * qi + (lane >> 3);
      const int jj = (lane & 7) * 4;
      float2 u0 = *(const float2*)&Tw[qq * 34 + jj];
      float2 u1 = *(const float2*)&Tw[qq * 34 + jj + 2];
      f32x4 o; o[0] = u0.x; o[1] = u0.y; o[2] = u1.x; o[3] = u1.y;
      *(f32x4*)&qkbase[qq * 1024 + 32 * c + jj] = o;
    }
  }
  mrun = fmaxf(mrun, __shfl_xor(mrun, 32));

  // ---- pass 2: recompute S, P = exp(S-m), PV ----
  float l = 0.f;
  f32x16 oa0 = {}, oa1 = {};
  for (int c = 0; c < 32; ++c) {
    bf16x8 kf[4];
#pragma unroll
    for (int kk = 0; kk < 4; ++kk)
      kf[kk] = ld_bf8(kbase + ((2 * kk + hi) * 1024 + 32 * c + r31) * 8);
    f32x16 acc = {};
#pragma unroll
    for (int kk = 0; kk < 4; ++kk)
      acc = mfma32(kf[kk], qf[kk], acc);
    float p[16];
#pragma unroll
    for (int r = 0; r < 16; ++r) {
      const int kr = (r & 3) + 8 * (r >> 2) + 4 * hi;
      const float v = acc[r] + bf2f(maskT[(32 * c + kr) * 1024 + q0 + r31]);
      p[r] = __expf(v - mrun);
      l += p[r];
    }
    // build PV A-frags: lane=q-row, elems k'=8hi+e (exchange halves w/ partner)
#pragma unroll
    for (int kk = 0; kk < 2; ++kk) {
      const float* pp = p + 8 * kk;
      const u32 a0 = pk2(pp[0], pp[1]), a1 = pk2(pp[2], pp[3]);  // own k' 4hi+0..3
      const u32 b0 = pk2(pp[4], pp[5]), b1 = pk2(pp[6], pp[7]);  // own k' 8+4hi+0..3
      const u32 s0 = hi ? a0 : b0, s1 = hi ? a1 : b1;
      const u32 t0 = __shfl_xor(s0, 32), t1 = __shfl_xor(s1, 32);
      union { u32 u[4]; bf16x8 v; } fr;
      fr.u[0] = hi ? t0 : a0;  fr.u[1] = hi ? t1 : a1;
      fr.u[2] = hi ? b0 : t0;  fr.u[3] = hi ? b1 : t1;
      const int s0i = 32 * c + 16 * kk + 8 * hi;
      bf16x8 v0 = ld_bf8(vbase + (((s0i >> 3) * 64) + r31) * 8);
      bf16x8 v1 = ld_bf8(vbase + (((s0i >> 3) * 64) + 32 + r31) * 8);
      oa0 = mfma32(fr.v, v0, oa0);
      oa1 = mfma32(fr.v, v1, oa1);
    }
  }
  l += __shfl_xor(l, 32);
  if (hi == 0) invl[w][r31] = 1.0f / l;
  // wave-private LDS: in-wave ordering suffices (no barrier)
#pragma unroll
  for (int r = 0; r < 16; ++r) {
    const int q = (r & 3) + 8 * (r >> 2) + 4 * hi;
    const float iv = invl[w][q];
    u16* wp = WV + (size_t)(bs0 + q0 + q) * 1024 + h * 64;
    wp[r31]      = f2bf(oa0[r] * iv);
    wp[32 + r31] = f2bf(oa1[r] * iv);
  }
}

// ---------------------------------------------------------------------------
// Output GEMM: out[8192,1024] = WV @ Wo^T + bo  (f32 out), 2-phase pipelined
// ---------------------------------------------------------------------------
__global__ __launch_bounds__(256) void out_gemm(
    const u16* __restrict__ Ab, const u16* __restrict__ Wb,
    const float* __restrict__ bias, float* __restrict__ outp) {
  __shared__ u16 As[2][128][32];
  __shared__ u16 Bs[2][128][32];
  const int tid  = threadIdx.x;
  const int lane = tid & 63;
  const int wid  = tid >> 6;
  const int c15  = lane & 15, c4 = lane >> 4;
  const int m0   = blockIdx.x * 128;
  const int n0   = blockIdx.y * 128;
  const int wrow = wid >> 1, wcol = wid & 1;
  const int srow = lane >> 2, scol = (lane & 3) * 8;

  const u16* aptr = Ab + (m0 + srow) * 1024 + scol;
  const u16* bptr = Wb + (n0 + srow) * 1024 + scol;

  f32x4 acc[4][4] = {};

#pragma unroll
  for (int j = 0; j < 2; ++j) {
    const int r = 64 * j + 16 * wid;
    gld_lds16(&As[0][r][0], aptr + r * 1024);
    gld_lds16(&Bs[0][r][0], bptr + r * 1024);
  }
  __syncthreads();

  int cur = 0;
  for (int k0 = 0; k0 < 1024; k0 += 32) {
    if (k0 + 32 < 1024) {
      const int nxt = cur ^ 1;
#pragma unroll
      for (int j = 0; j < 2; ++j) {
        const int r = 64 * j + 16 * wid;
        gld_lds16(&As[nxt][r][0], aptr + r * 1024 + k0 + 32);
        gld_lds16(&Bs[nxt][r][0], bptr + r * 1024 + k0 + 32);
      }
    }
    bf16x8 af[4], bfr[4];
#pragma unroll
    for (int a = 0; a < 4; ++a) af[a]  = ld_bf8(&As[cur][64 * wrow + 16 * a + c15][8 * c4]);
#pragma unroll
    for (int b = 0; b < 4; ++b) bfr[b] = ld_bf8(&Bs[cur][64 * wcol + 16 * b + c15][8 * c4]);
#pragma unroll
    for (int a = 0; a < 4; ++a)
#pragma unroll
      for (int b = 0; b < 4; ++b)
        acc[a][b] = mfma16(af[a], bfr[b], acc[a][b]);
    __syncthreads();
    cur ^= 1;
  }

#pragma unroll
  for (int a = 0; a < 4; ++a) {
    const int mg = m0 + 64 * wrow + 16 * a + 4 * c4;
#pragma unroll
    for (int b = 0; b < 4; ++b) {
      const int ng = n0 + 64 * wcol + 16 * b + c15;
      const float bi = bias[ng];
#pragma unroll
      for (int j = 0; j < 4; ++j)
        outp[(mg + j) * 1024 + ng] = acc[a][b][j] + bi;
    }
  }
}

// ---------------------------------------------------------------------------
extern "C" void kernel_launch(void* const* d_in, const int* in_sizes, int n_in,
                              void* d_out, int out_size, void* d_ws, size_t ws_size,
                              hipStream_t stream) {
  const float* x    = (const float*)d_in[0];
  const float* mask = (const float*)d_in[1];
  const float* Wq   = (const float*)d_in[2];
  const float* bq   = (const float*)d_in[3];
  const float* Wk   = (const float*)d_in[4];
  const float* Wv   = (const float*)d_in[5];
  const float* bv   = (const float*)d_in[6];
  const float* Wo   = (const float*)d_in[7];
  const float* bo   = (const float*)d_in[8];

  float* outp = (float*)d_out;
  float* qk   = outp + 8 * 1024 * 1024;      // second output

  // workspace (bf16 elements): ~92 MB total
  u16* ws    = (u16*)d_ws;
  u16* xb    = ws;                    // 8388608
  u16* Wqb   = xb  + 8388608;         // 1048576
  u16* Wkb   = Wqb + 1048576;
  u16* Wvb   = Wkb + 1048576;
  u16* Wob   = Wvb + 1048576;
  u16* Qt2   = Wob + 1048576;         // 8388608 ([bh][d>>3][s][d&7], scaled+bias)
  u16* Kt2   = Qt2 + 8388608;         // 8388608 ([bh][d>>3][s][d&7], scaled)
  u16* V2    = Kt2 + 8388608;         // 8388608 ([bh][s>>3][d][s&7])
  u16* WV    = V2  + 8388608;         // 8388608
  u16* maskT = WV  + 8388608;         // 1048576 (bf16, transposed [k][q])

  cvt_f32_bf16<<<4096, 256, 0, stream>>>(x,  xb,  8388608);
  cvt_f32_bf16<<<512,  256, 0, stream>>>(Wq, Wqb, 1048576);
  cvt_f32_bf16<<<512,  256, 0, stream>>>(Wk, Wkb, 1048576);
  cvt_f32_bf16<<<512,  256, 0, stream>>>(Wv, Wvb, 1048576);
  cvt_f32_bf16<<<512,  256, 0, stream>>>(Wo, Wob, 1048576);
  trans_mask<<<dim3(32, 32), 256, 0, stream>>>(mask, maskT);

  proj_gemm<<<dim3(64, 24), 256, 0, stream>>>(xb, Wqb, Wkb, Wvb, bq, bv, Qt2, Kt2, V2);
  attn_v2<<<dim3(4, 16, 8), 512, 0, stream>>>(Qt2, Kt2, V2, maskT, qk, WV);
  out_gemm<<<dim3(64, 8), 256, 0, stream>>>(WV, Wob, bo, outp);
}